// Round 13
// baseline (239.114 us; speedup 1.0000x reference)
//
#include <hip/hip_runtime.h>
#include <hip/hip_bf16.h>
#include <math.h>

typedef __bf16 bf16;
typedef __attribute__((ext_vector_type(8))) __bf16 bf16x8;
typedef __attribute__((ext_vector_type(4))) __bf16 bf16x4;
typedef __attribute__((ext_vector_type(4))) float f32x4;
typedef __attribute__((ext_vector_type(16))) float f32x16;
typedef __attribute__((ext_vector_type(4), aligned(4))) float f32x4u;  // unaligned vec load

#define B_  4
#define S_  2048
#define D_  1024
#define H_  16
#define DH_ 64
#define M_  (B_ * S_)   // 8192
#define LOG2E 1.44269504088896f

static __device__ __forceinline__ f32x4 mfma16(bf16x8 a, bf16x8 b, f32x4 c) {
  return __builtin_amdgcn_mfma_f32_16x16x32_bf16(a, b, c, 0, 0, 0);
}
static __device__ __forceinline__ f32x16 mfma32(bf16x8 a, bf16x8 b, f32x16 c) {
  return __builtin_amdgcn_mfma_f32_32x32x16_bf16(a, b, c, 0, 0, 0);
}

static __device__ __forceinline__ void gld_lds16(const bf16* g, bf16* l) {
  __builtin_amdgcn_global_load_lds(
      (const __attribute__((address_space(1))) void*)g,
      (__attribute__((address_space(3))) void*)l, 16, 0, 0);
}

static __device__ __forceinline__ unsigned pkbf(float a, float b) {
  union { struct { __bf16 lo, hi; } s; unsigned u; } x;
  x.s.lo = (bf16)a; x.s.hi = (bf16)b;
  return x.u;
}

// ---------------- f32 -> bf16 cast, both inputs in one dispatch ----------------
__global__ __launch_bounds__(256)
void cast2_kernel(const float* __restrict__ a, const float* __restrict__ bsrc,
                  bf16* __restrict__ oa, bf16* __restrict__ ob) {
  const int blk = blockIdx.x;
  const float* in = (blk < 8192) ? a : bsrc;
  bf16* out = (blk < 8192) ? oa : ob;
  size_t i = ((size_t)(blk & 8191) * 256 + threadIdx.x) * 4;
  float4 v = *(const float4*)(in + i);
  bf16x4 o = {(bf16)v.x, (bf16)v.y, (bf16)v.z, (bf16)v.w};
  *(bf16x4*)(out + i) = o;
}

// ---------------- transpose+cast all 4 weights: out[n][k] = bf16(in[k][n]) ----------------
__global__ __launch_bounds__(256)
void transpose_cast4_kernel(const float* __restrict__ w0, const float* __restrict__ w1,
                            const float* __restrict__ w2, const float* __restrict__ w3,
                            bf16* __restrict__ o0, bf16* __restrict__ o1,
                            bf16* __restrict__ o2, bf16* __restrict__ o3) {
  __shared__ float tile[32][33];
  const int z = blockIdx.z;
  const float* in = (z == 0) ? w0 : (z == 1) ? w1 : (z == 2) ? w2 : w3;
  bf16* out = (z == 0) ? o0 : (z == 1) ? o1 : (z == 2) ? o2 : o3;
  int n0 = blockIdx.x * 32, k0 = blockIdx.y * 32;
  int tx = threadIdx.x, ty = threadIdx.y;
#pragma unroll
  for (int j = 0; j < 32; j += 8)
    tile[ty + j][tx] = in[(size_t)(k0 + ty + j) * D_ + n0 + tx];
  __syncthreads();
#pragma unroll
  for (int j = 0; j < 32; j += 8)
    out[(size_t)(n0 + ty + j) * D_ + k0 + tx] = (bf16)tile[tx][ty + j];
}

// ---------------- bias table (exp2 domain, fixed-max fold): tab = bias*log2e - 64 ----------------
__global__ __launch_bounds__(256)
void bias_table_kernel(const float* __restrict__ rel_bias, float* __restrict__ tab) {
  int i = blockIdx.x * 256 + threadIdx.x;   // 16*4096 entries
  int h = i >> 12, dp = i & 4095;
  int rel = dp - 2047;                       // rel = s - t
  int bucket = (rel > 0) ? 16 : 0;
  int rp = rel < 0 ? -rel : rel;
  if (rp < 8) {
    bucket += rp;
  } else {
    // ln(rp/8)/ln(16)*8 == 2*log2(rp/8); exact at rp = 16,32,64,128 boundaries
    int large = 8 + (int)(2.0f * __log2f((float)rp * 0.125f));
    bucket += (large < 15 ? large : 15);
  }
  tab[i] = rel_bias[bucket * H_ + h] * LOG2E - 64.0f;   // fixed max M=64 folded in
}

// ---------------- fused Q/K/V projection GEMMs (z = 0,1,2), swizzled LDS ----------------
__global__ __launch_bounds__(256)
void proj_gemm_kernel(const bf16* __restrict__ Xq, const bf16* __restrict__ Xkv,
                      const bf16* __restrict__ Wq, const bf16* __restrict__ Wk,
                      const bf16* __restrict__ Wv,
                      bf16* __restrict__ Qb, bf16* __restrict__ Kb, bf16* __restrict__ Vt) {
  const int K = D_;
  __shared__ bf16 As[128][32];
  __shared__ bf16 Bs[128][32];
  const int z = blockIdx.z;
  const bf16* A  = (z == 0) ? Xq : Xkv;
  const bf16* Bt = (z == 0) ? Wq : (z == 1) ? Wk : Wv;
  const int tid = threadIdx.x;
  const int brow = blockIdx.y * 128, bcol = blockIdx.x * 128;
  const int wave = tid >> 6, lane = tid & 63;
  const int wr = (wave >> 1) * 64, wc = (wave & 1) * 64;
  const int lrow = lane & 15, lgrp = lane >> 4;

  f32x4 acc[4][4] = {};

  const int schunk = ((tid & 3) ^ ((tid >> 2) & 3)) * 8;   // pre-swizzled source chunk
  const bf16* ag = A + (size_t)(brow + (tid >> 2)) * K + schunk;
  const bf16* bg = Bt + (size_t)(bcol + (tid >> 2)) * K + schunk;
  const size_t rstep = (size_t)64 * K;       // (row+64)&3 == row&3: same swizzle key
  bf16* al = &As[0][0] + tid * 8;
  bf16* bl = &Bs[0][0] + tid * 8;

  const int rsw = (lrow & 3) << 4;           // read-side byte XOR
  const char* arp = (const char*)&As[0][0];
  const char* brp = (const char*)&Bs[0][0];

  for (int k0 = 0; k0 < K; k0 += 32) {
    __syncthreads();
    gld_lds16(ag + k0, al);
    gld_lds16(ag + k0 + rstep, al + 64 * 32);
    gld_lds16(bg + k0, bl);
    gld_lds16(bg + k0 + rstep, bl + 64 * 32);
    __syncthreads();
    bf16x8 af[4], bfr[4];
#pragma unroll
    for (int i = 0; i < 4; ++i) {
      af[i]  = *(const bf16x8*)(arp + (wr + i * 16 + lrow) * 64 + ((lgrp << 4) ^ rsw));
      bfr[i] = *(const bf16x8*)(brp + (wc + i * 16 + lrow) * 64 + ((lgrp << 4) ^ rsw));
    }
#pragma unroll
    for (int mi = 0; mi < 4; ++mi)
#pragma unroll
      for (int ni = 0; ni < 4; ++ni)
        acc[mi][ni] = mfma16(af[mi], bfr[ni], acc[mi][ni]);
  }

  const float scl = (z == 0) ? LOG2E : 1.0f;
#pragma unroll
  for (int mi = 0; mi < 4; ++mi) {
    const int rowb = brow + wr + mi * 16 + lgrp * 4;
#pragma unroll
    for (int ni = 0; ni < 4; ++ni) {
      const int col = bcol + wc + ni * 16 + lrow;
      const int hh = col >> 6, d = col & (DH_ - 1);
      if (z == 2) {
        // V^T store: rows r are consecutive s at fixed d -> one 8B store
        const int bb = rowb >> 11, s = rowb & (S_ - 1);
        bf16x4 pk = {(bf16)acc[mi][ni][0], (bf16)acc[mi][ni][1],
                     (bf16)acc[mi][ni][2], (bf16)acc[mi][ni][3]};
        *(bf16x4*)&Vt[((size_t)((bb * H_ + hh) * DH_ + d)) * S_ + s] = pk;
      } else {
#pragma unroll
        for (int r = 0; r < 4; ++r) {
          const float v = acc[mi][ni][r] * scl;
          const int m = rowb + r;
          const int bb = m >> 11, s = m & (S_ - 1);
          if (z == 0)
            Qb[((size_t)((bb * H_ + hh) * S_ + s)) * DH_ + d] = (bf16)v;
          else
            Kb[((size_t)((bb * H_ + hh) * S_ + s)) * DH_ + d] = (bf16)v;
        }
      }
    }
  }
}

// ---------------- output GEMM: out[MxN] f32 = Ab * Wo_t^T (now swizzled like proj) --------
__global__ __launch_bounds__(256)
void gemm_out_kernel(const bf16* __restrict__ A, const bf16* __restrict__ Bt,
                     float* __restrict__ Cout) {
  const int K = D_, N = D_;
  __shared__ bf16 As[128][32];
  __shared__ bf16 Bs[128][32];
  const int tid = threadIdx.x;
  const int brow = blockIdx.y * 128, bcol = blockIdx.x * 128;
  const int wave = tid >> 6, lane = tid & 63;
  const int wr = (wave >> 1) * 64, wc = (wave & 1) * 64;
  const int lrow = lane & 15, lgrp = lane >> 4;

  f32x4 acc[4][4] = {};

  const int schunk = ((tid & 3) ^ ((tid >> 2) & 3)) * 8;   // pre-swizzled source chunk
  const bf16* ag = A + (size_t)(brow + (tid >> 2)) * K + schunk;
  const bf16* bg = Bt + (size_t)(bcol + (tid >> 2)) * K + schunk;
  const size_t rstep = (size_t)64 * K;
  bf16* al = &As[0][0] + tid * 8;
  bf16* bl = &Bs[0][0] + tid * 8;

  const int rsw = (lrow & 3) << 4;           // read-side byte XOR
  const char* arp = (const char*)&As[0][0];
  const char* brp = (const char*)&Bs[0][0];

  for (int k0 = 0; k0 < K; k0 += 32) {
    __syncthreads();
    gld_lds16(ag + k0, al);
    gld_lds16(ag + k0 + rstep, al + 64 * 32);
    gld_lds16(bg + k0, bl);
    gld_lds16(bg + k0 + rstep, bl + 64 * 32);
    __syncthreads();
    bf16x8 af[4], bfr[4];
#pragma unroll
    for (int i = 0; i < 4; ++i) {
      af[i]  = *(const bf16x8*)(arp + (wr + i * 16 + lrow) * 64 + ((lgrp << 4) ^ rsw));
      bfr[i] = *(const bf16x8*)(brp + (wc + i * 16 + lrow) * 64 + ((lgrp << 4) ^ rsw));
    }
#pragma unroll
    for (int mi = 0; mi < 4; ++mi)
#pragma unroll
      for (int ni = 0; ni < 4; ++ni)
        acc[mi][ni] = mfma16(af[mi], bfr[ni], acc[mi][ni]);
  }

#pragma unroll
  for (int mi = 0; mi < 4; ++mi) {
    const int rowb = brow + wr + mi * 16 + lgrp * 4;
#pragma unroll
    for (int ni = 0; ni < 4; ++ni) {
      const int col = bcol + wc + ni * 16 + lrow;
#pragma unroll
      for (int r = 0; r < 4; ++r)
        Cout[(size_t)(rowb + r) * N + col] = acc[mi][ni][r];
    }
  }
}

// ---------------- flash attention v7 + T5 setprio around MFMA clusters ----------------
// 1024 blocks (XCD-swizzled), 256 thr = 4 waves; lane owns 1 q-row.
// Single LDS arena: K0[0,8K) K1[8K,16K) V0[16K,24K) V1[24K,32K).
__global__ __launch_bounds__(256, 4)
void attn_kernel(const bf16* __restrict__ Q, const bf16* __restrict__ Kb,
                 const bf16* __restrict__ Vt, const float* __restrict__ tab,
                 bf16* __restrict__ Oa) {
  __shared__ bf16 SB[4][4096];   // 8KB regions: K0,K1,V0,V1; 32 rows x 256B, swizzled

  const int bid = blockIdx.x;
  const int w = ((bid & 7) << 7) + (bid >> 3);   // XCD chunk of 128 = 8 full (b,h) panels
  const int qt = w & 15, h = (w >> 4) & 15, b = w >> 8;
  const int tid = threadIdx.x;
  const int wave = tid >> 6, lane = tid & 63;
  const int l31 = lane & 31;
  const int hi = lane >> 5;       // 0/1
  const int t = qt * 128 + wave * 32 + l31;   // this lane's q-row

  const bf16* Qp = Q + (size_t)(b * H_ + h) * S_ * DH_;
  const bf16* Kp = Kb + (size_t)(b * H_ + h) * S_ * DH_;
  const bf16* Vp = Vt + (size_t)(b * H_ + h) * DH_ * S_;
  const float* btb = tab + h * 4096 + 2047 - t;

  // ---- staging: thread stages dst bytes tid*16 (+4096) per 8KB region
  const int row0 = tid >> 4, row1 = row0 + 16;
  const int colS = (tid & 15) << 4;
  const int col0 = colS ^ ((row0 & 15) << 4);
  const int col1 = colS ^ ((row1 & 15) << 4);
  const bf16* ks0 = Kp + (size_t)(row0 + 32 * (col0 >> 7)) * DH_ + ((col0 & 127) >> 1);
  const bf16* ks1 = Kp + (size_t)(row1 + 32 * (col1 >> 7)) * DH_ + ((col1 & 127) >> 1);
  const bf16* vs0 = Vp + (size_t)(row0 + 32 * (col0 >> 7)) * S_ + ((col0 & 127) >> 1);
  const bf16* vs1 = Vp + (size_t)(row1 + 32 * (col1 >> 7)) * S_ + ((col1 & 127) >> 1);
  bf16* sd = &SB[0][0] + tid * 8;   // + {0,2048} elems within region, + region*4096

  // ---- precomputed LDS read pointers: ra[c][sub]; buf/V via literal offsets
  const int swz = (l31 & 15) << 4;
  const char* rb = (const char*)&SB[0][0] + l31 * 256;
  const char* ra[4][2];
#pragma unroll
  for (int c = 0; c < 4; ++c)
#pragma unroll
    for (int sub = 0; sub < 2; ++sub)
      ra[c][sub] = rb + ((c * 32 + hi * 16 + sub * 128) ^ swz);

  // ---- Q fragments (B-operand): B[row=q=lane&31][k = hi*8+j], per d-chunk c (K=16)
  bf16x8 qf[4];
#pragma unroll
  for (int c = 0; c < 4; ++c)
    qf[c] = *(const bf16x8*)&Qp[(size_t)t * DH_ + c * 16 + hi * 8];

  float l_r = 0.f;
  f32x16 o0 = {}, o1 = {};   // PV accum: d 0..31 / 32..63, q = lane&31 (col)

  // prologue: stage tile 0 into buf 0
  gld_lds16(ks0, sd); gld_lds16(ks1, sd + 2048);
  gld_lds16(vs0, sd + 8192); gld_lds16(vs1, sd + 10240);
  __syncthreads();

  // one KV tile; BUF is a literal so every ds_read offset is an immediate
#define ATTN_TILE(BUF, S0)                                                        \
  {                                                                               \
    if ((S0) + 64 < S_) {                                                         \
      const int nb = (BUF) ^ 1;                                                   \
      gld_lds16(ks0 + (size_t)((S0) + 64) * DH_, sd + nb * 4096);                 \
      gld_lds16(ks1 + (size_t)((S0) + 64) * DH_, sd + nb * 4096 + 2048);          \
      gld_lds16(vs0 + ((S0) + 64), sd + nb * 4096 + 8192);                        \
      gld_lds16(vs1 + ((S0) + 64), sd + nb * 4096 + 10240);                       \
    }                                                                             \
    f32x16 sc0, sc1;                                                              \
    _Pragma("unroll")                                                             \
    for (int g = 0; g < 4; ++g) {                                                 \
      f32x4u b0 = *(const f32x4u*)(btb + (S0) + 8 * g + 4 * hi);                  \
      f32x4u b1 = *(const f32x4u*)(btb + (S0) + 32 + 8 * g + 4 * hi);             \
      _Pragma("unroll")                                                           \
      for (int v = 0; v < 4; ++v) { sc0[4 * g + v] = b0[v]; sc1[4 * g + v] = b1[v]; } \
    }                                                                             \
    __builtin_amdgcn_s_setprio(1);                                                \
    _Pragma("unroll")                                                             \
    for (int c = 0; c < 4; ++c) {                                                 \
      bf16x8 k0 = *(const bf16x8*)(ra[c][0] + (BUF) * 8192);                      \
      bf16x8 k1 = *(const bf16x8*)(ra[c][1] + (BUF) * 8192);                      \
      sc0 = mfma32(k0, qf[c], sc0);                                               \
      sc1 = mfma32(k1, qf[c], sc1);                                               \
    }                                                                             \
    __builtin_amdgcn_s_setprio(0);                                                \
    unsigned pw[16];                                                              \
    float q0s = 0.f, q1s = 0.f, q2s = 0.f, q3s = 0.f;                             \
    _Pragma("unroll")                                                             \
    for (int r2 = 0; r2 < 8; ++r2) {                                              \
      float a0 = __builtin_amdgcn_exp2f(sc0[2 * r2]);                             \
      float a1 = __builtin_amdgcn_exp2f(sc0[2 * r2 + 1]);                         \
      float c0 = __builtin_amdgcn_exp2f(sc1[2 * r2]);                             \
      float c1 = __builtin_amdgcn_exp2f(sc1[2 * r2 + 1]);                         \
      q0s += a0; q1s += a1; q2s += c0; q3s += c1;                                 \
      pw[r2] = pkbf(a0, a1);                                                      \
      pw[8 + r2] = pkbf(c0, c1);                                                  \
    }                                                                             \
    l_r += (q0s + q1s) + (q2s + q3s);                                             \
    /* all 8 cross-half exchanges upfront (overlapping lgkm waits) */             \
    unsigned sh[8];                                                               \
    _Pragma("unroll")                                                             \
    for (int g = 0; g < 4; ++g) {                                                 \
      const int base = (g & 1) * 4 + (g >> 1) * 8;                                \
      sh[2 * g]     = __shfl_xor(hi ? pw[base + 0] : pw[base + 2], 32);           \
      sh[2 * g + 1] = __shfl_xor(hi ? pw[base + 1] : pw[base + 3], 32);           \
    }                                                                             \
    __builtin_amdgcn_s_setprio(1);                                                \
    _Pragma("unroll")                                                             \
    for (int g = 0; g < 4; ++g) {                                                 \
      const int base = (g & 1) * 4 + (g >> 1) * 8;                                \
      int4 bi = { (int)(hi ? sh[2 * g]     : pw[base + 0]),                       \
                  (int)(hi ? sh[2 * g + 1] : pw[base + 1]),                       \
                  (int)(hi ? pw[base + 2] : sh[2 * g]),                           \
                  (int)(hi ? pw[base + 3] : sh[2 * g + 1]) };                     \
      bf16x8 pb = *(bf16x8*)&bi;                                                  \
      bf16x8 v0 = *(const bf16x8*)(ra[g][0] + 16384 + (BUF) * 8192);              \
      bf16x8 v1 = *(const bf16x8*)(ra[g][1] + 16384 + (BUF) * 8192);              \
      o0 = mfma32(v0, pb, o0);                                                    \
      o1 = mfma32(v1, pb, o1);                                                    \
    }                                                                             \
    __builtin_amdgcn_s_setprio(0);                                                \
    __syncthreads();                                                              \
  }

  for (int s0 = 0; s0 < S_; s0 += 128) {
    ATTN_TILE(0, s0)
    ATTN_TILE(1, s0 + 64)
  }
#undef ATTN_TILE

  // ---- finalize: one shuffle for the full row-sum; per-lane scalar normalize
  l_r += __shfl_xor(l_r, 32);
  const float inv = 1.0f / l_r;
  bf16* Ob = Oa + ((size_t)(b * S_ + t)) * D_ + h * DH_;
#pragma unroll
  for (int g = 0; g < 4; ++g) {
    bf16x4 u0 = {(bf16)(o0[4 * g + 0] * inv), (bf16)(o0[4 * g + 1] * inv),
                 (bf16)(o0[4 * g + 2] * inv), (bf16)(o0[4 * g + 3] * inv)};
    *(bf16x4*)&Ob[8 * g + 4 * hi] = u0;
    bf16x4 u1 = {(bf16)(o1[4 * g + 0] * inv), (bf16)(o1[4 * g + 1] * inv),
                 (bf16)(o1[4 * g + 2] * inv), (bf16)(o1[4 * g + 3] * inv)};
    *(bf16x4*)&Ob[32 + 8 * g + 4 * hi] = u1;
  }
}

// ---------------- launch ----------------
extern "C" void kernel_launch(void* const* d_in, const int* in_sizes, int n_in,
                              void* d_out, int out_size, void* d_ws, size_t ws_size,
                              hipStream_t stream) {
  const float* Xq   = (const float*)d_in[0];
  const float* Xkv  = (const float*)d_in[1];
  const float* Wq   = (const float*)d_in[2];
  const float* Wk   = (const float*)d_in[3];
  const float* Wv   = (const float*)d_in[4];
  const float* Wo   = (const float*)d_in[5];
  const float* relb = (const float*)d_in[6];
  float* out = (float*)d_out;

  char* ws = (char*)d_ws;
  const size_t SZ_X = (size_t)M_ * D_ * 2;   // 16 MB
  const size_t SZ_W = (size_t)D_ * D_ * 2;   // 2 MB
  bf16* Xq_b  = (bf16*)(ws);
  bf16* Xkv_b = (bf16*)(ws + SZ_X);
  bf16* Wq_t  = (bf16*)(ws + 2 * SZ_X);
  bf16* Wk_t  = (bf16*)(ws + 2 * SZ_X + SZ_W);
  bf16* Wv_t  = (bf16*)(ws + 2 * SZ_X + 2 * SZ_W);
  bf16* Wo_t  = (bf16*)(ws + 2 * SZ_X + 3 * SZ_W);
  bf16* Qb    = (bf16*)(ws + 2 * SZ_X + 4 * SZ_W);
  bf16* Kbuf  = (bf16*)(ws + 3 * SZ_X + 4 * SZ_W);
  bf16* Vt    = (bf16*)(ws + 4 * SZ_X + 4 * SZ_W);
  bf16* Ab    = (bf16*)(ws + 5 * SZ_X + 4 * SZ_W);
  float* tab  = (float*)(ws + 6 * SZ_X + 4 * SZ_W);  // 16*4096 f32

  cast2_kernel<<<16384, 256, 0, stream>>>(Xq, Xkv, Xq_b, Xkv_b);
  transpose_cast4_kernel<<<dim3(32, 32, 4), dim3(32, 8), 0, stream>>>(
      Wq, Wk, Wv, Wo, Wq_t, Wk_t, Wv_t, Wo_t);
  bias_table_kernel<<<256, 256, 0, stream>>>(relb, tab);

  proj_gemm_kernel<<<dim3(8, 64, 3), 256, 0, stream>>>(
      Xq_b, Xkv_b, Wq_t, Wk_t, Wv_t, Qb, Kbuf, Vt);
  attn_kernel<<<1024, 256, 0, stream>>>(Qb, Kbuf, Vt, tab, Ab);
  gemm_out_kernel<<<dim3(8, 64), 256, 0, stream>>>(Ab, Wo_t, out);
}

// Round 14
// 228.117 us; speedup vs baseline: 1.0482x; 1.0482x over previous
//
#include <hip/hip_runtime.h>
#include <hip/hip_bf16.h>
#include <math.h>

typedef __bf16 bf16;
typedef __attribute__((ext_vector_type(8))) __bf16 bf16x8;
typedef __attribute__((ext_vector_type(4))) __bf16 bf16x4;
typedef __attribute__((ext_vector_type(4))) float f32x4;
typedef __attribute__((ext_vector_type(16))) float f32x16;
typedef __attribute__((ext_vector_type(4), aligned(4))) float f32x4u;  // unaligned vec load

#define B_  4
#define S_  2048
#define D_  1024
#define H_  16
#define DH_ 64
#define M_  (B_ * S_)   // 8192
#define LOG2E 1.44269504088896f

static __device__ __forceinline__ f32x4 mfma16(bf16x8 a, bf16x8 b, f32x4 c) {
  return __builtin_amdgcn_mfma_f32_16x16x32_bf16(a, b, c, 0, 0, 0);
}
static __device__ __forceinline__ f32x16 mfma32(bf16x8 a, bf16x8 b, f32x16 c) {
  return __builtin_amdgcn_mfma_f32_32x32x16_bf16(a, b, c, 0, 0, 0);
}

static __device__ __forceinline__ void gld_lds16(const bf16* g, bf16* l) {
  __builtin_amdgcn_global_load_lds(
      (const __attribute__((address_space(1))) void*)g,
      (__attribute__((address_space(3))) void*)l, 16, 0, 0);
}

static __device__ __forceinline__ unsigned pkbf(float a, float b) {
  union { struct { __bf16 lo, hi; } s; unsigned u; } x;
  x.s.lo = (bf16)a; x.s.hi = (bf16)b;
  return x.u;
}

// ---------------- f32 -> bf16 cast, both inputs in one dispatch ----------------
__global__ __launch_bounds__(256)
void cast2_kernel(const float* __restrict__ a, const float* __restrict__ bsrc,
                  bf16* __restrict__ oa, bf16* __restrict__ ob) {
  const int blk = blockIdx.x;
  const float* in = (blk < 8192) ? a : bsrc;
  bf16* out = (blk < 8192) ? oa : ob;
  size_t i = ((size_t)(blk & 8191) * 256 + threadIdx.x) * 4;
  float4 v = *(const float4*)(in + i);
  bf16x4 o = {(bf16)v.x, (bf16)v.y, (bf16)v.z, (bf16)v.w};
  *(bf16x4*)(out + i) = o;
}

// ---------------- transpose+cast all 4 weights: out[n][k] = bf16(in[k][n]) ----------------
__global__ __launch_bounds__(256)
void transpose_cast4_kernel(const float* __restrict__ w0, const float* __restrict__ w1,
                            const float* __restrict__ w2, const float* __restrict__ w3,
                            bf16* __restrict__ o0, bf16* __restrict__ o1,
                            bf16* __restrict__ o2, bf16* __restrict__ o3) {
  __shared__ float tile[32][33];
  const int z = blockIdx.z;
  const float* in = (z == 0) ? w0 : (z == 1) ? w1 : (z == 2) ? w2 : w3;
  bf16* out = (z == 0) ? o0 : (z == 1) ? o1 : (z == 2) ? o2 : o3;
  int n0 = blockIdx.x * 32, k0 = blockIdx.y * 32;
  int tx = threadIdx.x, ty = threadIdx.y;
#pragma unroll
  for (int j = 0; j < 32; j += 8)
    tile[ty + j][tx] = in[(size_t)(k0 + ty + j) * D_ + n0 + tx];
  __syncthreads();
#pragma unroll
  for (int j = 0; j < 32; j += 8)
    out[(size_t)(n0 + ty + j) * D_ + k0 + tx] = (bf16)tile[tx][ty + j];
}

// ---------------- bias table (exp2 domain, fixed-max fold): tab = bias*log2e - 64 ----------------
__global__ __launch_bounds__(256)
void bias_table_kernel(const float* __restrict__ rel_bias, float* __restrict__ tab) {
  int i = blockIdx.x * 256 + threadIdx.x;   // 16*4096 entries
  int h = i >> 12, dp = i & 4095;
  int rel = dp - 2047;                       // rel = s - t
  int bucket = (rel > 0) ? 16 : 0;
  int rp = rel < 0 ? -rel : rel;
  if (rp < 8) {
    bucket += rp;
  } else {
    // ln(rp/8)/ln(16)*8 == 2*log2(rp/8); exact at rp = 16,32,64,128 boundaries
    int large = 8 + (int)(2.0f * __log2f((float)rp * 0.125f));
    bucket += (large < 15 ? large : 15);
  }
  tab[i] = rel_bias[bucket * H_ + h] * LOG2E - 64.0f;   // fixed max M=64 folded in
}

// ---------------- fused Q/K/V projection GEMMs (z = 0,1,2), swizzled LDS ----------------
__global__ __launch_bounds__(256)
void proj_gemm_kernel(const bf16* __restrict__ Xq, const bf16* __restrict__ Xkv,
                      const bf16* __restrict__ Wq, const bf16* __restrict__ Wk,
                      const bf16* __restrict__ Wv,
                      bf16* __restrict__ Qb, bf16* __restrict__ Kb, bf16* __restrict__ Vt) {
  const int K = D_;
  __shared__ bf16 As[128][32];
  __shared__ bf16 Bs[128][32];
  const int z = blockIdx.z;
  const bf16* A  = (z == 0) ? Xq : Xkv;
  const bf16* Bt = (z == 0) ? Wq : (z == 1) ? Wk : Wv;
  const int tid = threadIdx.x;
  const int brow = blockIdx.y * 128, bcol = blockIdx.x * 128;
  const int wave = tid >> 6, lane = tid & 63;
  const int wr = (wave >> 1) * 64, wc = (wave & 1) * 64;
  const int lrow = lane & 15, lgrp = lane >> 4;

  f32x4 acc[4][4] = {};

  const int schunk = ((tid & 3) ^ ((tid >> 2) & 3)) * 8;   // pre-swizzled source chunk
  const bf16* ag = A + (size_t)(brow + (tid >> 2)) * K + schunk;
  const bf16* bg = Bt + (size_t)(bcol + (tid >> 2)) * K + schunk;
  const size_t rstep = (size_t)64 * K;       // (row+64)&3 == row&3: same swizzle key
  bf16* al = &As[0][0] + tid * 8;
  bf16* bl = &Bs[0][0] + tid * 8;

  const int rsw = (lrow & 3) << 4;           // read-side byte XOR
  const char* arp = (const char*)&As[0][0];
  const char* brp = (const char*)&Bs[0][0];

  for (int k0 = 0; k0 < K; k0 += 32) {
    __syncthreads();
    gld_lds16(ag + k0, al);
    gld_lds16(ag + k0 + rstep, al + 64 * 32);
    gld_lds16(bg + k0, bl);
    gld_lds16(bg + k0 + rstep, bl + 64 * 32);
    __syncthreads();
    bf16x8 af[4], bfr[4];
#pragma unroll
    for (int i = 0; i < 4; ++i) {
      af[i]  = *(const bf16x8*)(arp + (wr + i * 16 + lrow) * 64 + ((lgrp << 4) ^ rsw));
      bfr[i] = *(const bf16x8*)(brp + (wc + i * 16 + lrow) * 64 + ((lgrp << 4) ^ rsw));
    }
#pragma unroll
    for (int mi = 0; mi < 4; ++mi)
#pragma unroll
      for (int ni = 0; ni < 4; ++ni)
        acc[mi][ni] = mfma16(af[mi], bfr[ni], acc[mi][ni]);
  }

  const float scl = (z == 0) ? LOG2E : 1.0f;
#pragma unroll
  for (int mi = 0; mi < 4; ++mi) {
    const int rowb = brow + wr + mi * 16 + lgrp * 4;
#pragma unroll
    for (int ni = 0; ni < 4; ++ni) {
      const int col = bcol + wc + ni * 16 + lrow;
      const int hh = col >> 6, d = col & (DH_ - 1);
      if (z == 2) {
        // V^T store: rows r are consecutive s at fixed d -> one 8B store
        const int bb = rowb >> 11, s = rowb & (S_ - 1);
        bf16x4 pk = {(bf16)acc[mi][ni][0], (bf16)acc[mi][ni][1],
                     (bf16)acc[mi][ni][2], (bf16)acc[mi][ni][3]};
        *(bf16x4*)&Vt[((size_t)((bb * H_ + hh) * DH_ + d)) * S_ + s] = pk;
      } else {
#pragma unroll
        for (int r = 0; r < 4; ++r) {
          const float v = acc[mi][ni][r] * scl;
          const int m = rowb + r;
          const int bb = m >> 11, s = m & (S_ - 1);
          if (z == 0)
            Qb[((size_t)((bb * H_ + hh) * S_ + s)) * DH_ + d] = (bf16)v;
          else
            Kb[((size_t)((bb * H_ + hh) * S_ + s)) * DH_ + d] = (bf16)v;
        }
      }
    }
  }
}

// ---------------- output GEMM: out[MxN] f32 = Ab * Wo_t^T (swizzled like proj) --------
__global__ __launch_bounds__(256)
void gemm_out_kernel(const bf16* __restrict__ A, const bf16* __restrict__ Bt,
                     float* __restrict__ Cout) {
  const int K = D_, N = D_;
  __shared__ bf16 As[128][32];
  __shared__ bf16 Bs[128][32];
  const int tid = threadIdx.x;
  const int brow = blockIdx.y * 128, bcol = blockIdx.x * 128;
  const int wave = tid >> 6, lane = tid & 63;
  const int wr = (wave >> 1) * 64, wc = (wave & 1) * 64;
  const int lrow = lane & 15, lgrp = lane >> 4;

  f32x4 acc[4][4] = {};

  const int schunk = ((tid & 3) ^ ((tid >> 2) & 3)) * 8;   // pre-swizzled source chunk
  const bf16* ag = A + (size_t)(brow + (tid >> 2)) * K + schunk;
  const bf16* bg = Bt + (size_t)(bcol + (tid >> 2)) * K + schunk;
  const size_t rstep = (size_t)64 * K;
  bf16* al = &As[0][0] + tid * 8;
  bf16* bl = &Bs[0][0] + tid * 8;

  const int rsw = (lrow & 3) << 4;           // read-side byte XOR
  const char* arp = (const char*)&As[0][0];
  const char* brp = (const char*)&Bs[0][0];

  for (int k0 = 0; k0 < K; k0 += 32) {
    __syncthreads();
    gld_lds16(ag + k0, al);
    gld_lds16(ag + k0 + rstep, al + 64 * 32);
    gld_lds16(bg + k0, bl);
    gld_lds16(bg + k0 + rstep, bl + 64 * 32);
    __syncthreads();
    bf16x8 af[4], bfr[4];
#pragma unroll
    for (int i = 0; i < 4; ++i) {
      af[i]  = *(const bf16x8*)(arp + (wr + i * 16 + lrow) * 64 + ((lgrp << 4) ^ rsw));
      bfr[i] = *(const bf16x8*)(brp + (wc + i * 16 + lrow) * 64 + ((lgrp << 4) ^ rsw));
    }
#pragma unroll
    for (int mi = 0; mi < 4; ++mi)
#pragma unroll
      for (int ni = 0; ni < 4; ++ni)
        acc[mi][ni] = mfma16(af[mi], bfr[ni], acc[mi][ni]);
  }

#pragma unroll
  for (int mi = 0; mi < 4; ++mi) {
    const int rowb = brow + wr + mi * 16 + lgrp * 4;
#pragma unroll
    for (int ni = 0; ni < 4; ++ni) {
      const int col = bcol + wc + ni * 16 + lrow;
#pragma unroll
      for (int r = 0; r < 4; ++r)
        Cout[(size_t)(rowb + r) * N + col] = acc[mi][ni][r];
    }
  }
}

// ---------------- flash attention v7 (verbatim round-12 known-good, no setprio) ----------
// 1024 blocks (XCD-swizzled), 256 thr = 4 waves; lane owns 1 q-row.
// Single LDS arena: K0[0,8K) K1[8K,16K) V0[16K,24K) V1[24K,32K).
__global__ __launch_bounds__(256, 4)
void attn_kernel(const bf16* __restrict__ Q, const bf16* __restrict__ Kb,
                 const bf16* __restrict__ Vt, const float* __restrict__ tab,
                 bf16* __restrict__ Oa) {
  __shared__ bf16 SB[4][4096];   // 8KB regions: K0,K1,V0,V1; 32 rows x 256B, swizzled

  const int bid = blockIdx.x;
  const int w = ((bid & 7) << 7) + (bid >> 3);   // XCD chunk of 128 = 8 full (b,h) panels
  const int qt = w & 15, h = (w >> 4) & 15, b = w >> 8;
  const int tid = threadIdx.x;
  const int wave = tid >> 6, lane = tid & 63;
  const int l31 = lane & 31;
  const int hi = lane >> 5;       // 0/1
  const int t = qt * 128 + wave * 32 + l31;   // this lane's q-row

  const bf16* Qp = Q + (size_t)(b * H_ + h) * S_ * DH_;
  const bf16* Kp = Kb + (size_t)(b * H_ + h) * S_ * DH_;
  const bf16* Vp = Vt + (size_t)(b * H_ + h) * DH_ * S_;
  const float* btb = tab + h * 4096 + 2047 - t;

  // ---- staging: thread stages dst bytes tid*16 (+4096) per 8KB region
  const int row0 = tid >> 4, row1 = row0 + 16;
  const int colS = (tid & 15) << 4;
  const int col0 = colS ^ ((row0 & 15) << 4);
  const int col1 = colS ^ ((row1 & 15) << 4);
  const bf16* ks0 = Kp + (size_t)(row0 + 32 * (col0 >> 7)) * DH_ + ((col0 & 127) >> 1);
  const bf16* ks1 = Kp + (size_t)(row1 + 32 * (col1 >> 7)) * DH_ + ((col1 & 127) >> 1);
  const bf16* vs0 = Vp + (size_t)(row0 + 32 * (col0 >> 7)) * S_ + ((col0 & 127) >> 1);
  const bf16* vs1 = Vp + (size_t)(row1 + 32 * (col1 >> 7)) * S_ + ((col1 & 127) >> 1);
  bf16* sd = &SB[0][0] + tid * 8;   // + {0,2048} elems within region, + region*4096

  // ---- precomputed LDS read pointers: ra[c][sub]; buf/V via literal offsets
  const int swz = (l31 & 15) << 4;
  const char* rb = (const char*)&SB[0][0] + l31 * 256;
  const char* ra[4][2];
#pragma unroll
  for (int c = 0; c < 4; ++c)
#pragma unroll
    for (int sub = 0; sub < 2; ++sub)
      ra[c][sub] = rb + ((c * 32 + hi * 16 + sub * 128) ^ swz);

  // ---- Q fragments (B-operand): B[row=q=lane&31][k = hi*8+j], per d-chunk c (K=16)
  bf16x8 qf[4];
#pragma unroll
  for (int c = 0; c < 4; ++c)
    qf[c] = *(const bf16x8*)&Qp[(size_t)t * DH_ + c * 16 + hi * 8];

  float l_r = 0.f;
  f32x16 o0 = {}, o1 = {};   // PV accum: d 0..31 / 32..63, q = lane&31 (col)

  // prologue: stage tile 0 into buf 0
  gld_lds16(ks0, sd); gld_lds16(ks1, sd + 2048);
  gld_lds16(vs0, sd + 8192); gld_lds16(vs1, sd + 10240);
  __syncthreads();

  // one KV tile; BUF is a literal so every ds_read offset is an immediate
#define ATTN_TILE(BUF, S0)                                                        \
  {                                                                               \
    if ((S0) + 64 < S_) {                                                         \
      const int nb = (BUF) ^ 1;                                                   \
      gld_lds16(ks0 + (size_t)((S0) + 64) * DH_, sd + nb * 4096);                 \
      gld_lds16(ks1 + (size_t)((S0) + 64) * DH_, sd + nb * 4096 + 2048);          \
      gld_lds16(vs0 + ((S0) + 64), sd + nb * 4096 + 8192);                        \
      gld_lds16(vs1 + ((S0) + 64), sd + nb * 4096 + 10240);                       \
    }                                                                             \
    f32x16 sc0, sc1;                                                              \
    _Pragma("unroll")                                                             \
    for (int g = 0; g < 4; ++g) {                                                 \
      f32x4u b0 = *(const f32x4u*)(btb + (S0) + 8 * g + 4 * hi);                  \
      f32x4u b1 = *(const f32x4u*)(btb + (S0) + 32 + 8 * g + 4 * hi);             \
      _Pragma("unroll")                                                           \
      for (int v = 0; v < 4; ++v) { sc0[4 * g + v] = b0[v]; sc1[4 * g + v] = b1[v]; } \
    }                                                                             \
    _Pragma("unroll")                                                             \
    for (int c = 0; c < 4; ++c) {                                                 \
      bf16x8 k0 = *(const bf16x8*)(ra[c][0] + (BUF) * 8192);                      \
      bf16x8 k1 = *(const bf16x8*)(ra[c][1] + (BUF) * 8192);                      \
      sc0 = mfma32(k0, qf[c], sc0);                                               \
      sc1 = mfma32(k1, qf[c], sc1);                                               \
    }                                                                             \
    unsigned pw[16];                                                              \
    float q0s = 0.f, q1s = 0.f, q2s = 0.f, q3s = 0.f;                             \
    _Pragma("unroll")                                                             \
    for (int r2 = 0; r2 < 8; ++r2) {                                              \
      float a0 = __builtin_amdgcn_exp2f(sc0[2 * r2]);                             \
      float a1 = __builtin_amdgcn_exp2f(sc0[2 * r2 + 1]);                         \
      float c0 = __builtin_amdgcn_exp2f(sc1[2 * r2]);                             \
      float c1 = __builtin_amdgcn_exp2f(sc1[2 * r2 + 1]);                         \
      q0s += a0; q1s += a1; q2s += c0; q3s += c1;                                 \
      pw[r2] = pkbf(a0, a1);                                                      \
      pw[8 + r2] = pkbf(c0, c1);                                                  \
    }                                                                             \
    l_r += (q0s + q1s) + (q2s + q3s);                                             \
    /* all 8 cross-half exchanges upfront (overlapping lgkm waits) */             \
    unsigned sh[8];                                                               \
    _Pragma("unroll")                                                             \
    for (int g = 0; g < 4; ++g) {                                                 \
      const int base = (g & 1) * 4 + (g >> 1) * 8;                                \
      sh[2 * g]     = __shfl_xor(hi ? pw[base + 0] : pw[base + 2], 32);           \
      sh[2 * g + 1] = __shfl_xor(hi ? pw[base + 1] : pw[base + 3], 32);           \
    }                                                                             \
    _Pragma("unroll")                                                             \
    for (int g = 0; g < 4; ++g) {                                                 \
      const int base = (g & 1) * 4 + (g >> 1) * 8;                                \
      int4 bi = { (int)(hi ? sh[2 * g]     : pw[base + 0]),                       \
                  (int)(hi ? sh[2 * g + 1] : pw[base + 1]),                       \
                  (int)(hi ? pw[base + 2] : sh[2 * g]),                           \
                  (int)(hi ? pw[base + 3] : sh[2 * g + 1]) };                     \
      bf16x8 pb = *(bf16x8*)&bi;                                                  \
      bf16x8 v0 = *(const bf16x8*)(ra[g][0] + 16384 + (BUF) * 8192);              \
      bf16x8 v1 = *(const bf16x8*)(ra[g][1] + 16384 + (BUF) * 8192);              \
      o0 = mfma32(v0, pb, o0);                                                    \
      o1 = mfma32(v1, pb, o1);                                                    \
    }                                                                             \
    __syncthreads();                                                              \
  }

  for (int s0 = 0; s0 < S_; s0 += 128) {
    ATTN_TILE(0, s0)
    ATTN_TILE(1, s0 + 64)
  }
#undef ATTN_TILE

  // ---- finalize: one shuffle for the full row-sum; per-lane scalar normalize
  l_r += __shfl_xor(l_r, 32);
  const float inv = 1.0f / l_r;
  bf16* Ob = Oa + ((size_t)(b * S_ + t)) * D_ + h * DH_;
#pragma unroll
  for (int g = 0; g < 4; ++g) {
    bf16x4 u0 = {(bf16)(o0[4 * g + 0] * inv), (bf16)(o0[4 * g + 1] * inv),
                 (bf16)(o0[4 * g + 2] * inv), (bf16)(o0[4 * g + 3] * inv)};
    *(bf16x4*)&Ob[8 * g + 4 * hi] = u0;
    bf16x4 u1 = {(bf16)(o1[4 * g + 0] * inv), (bf16)(o1[4 * g + 1] * inv),
                 (bf16)(o1[4 * g + 2] * inv), (bf16)(o1[4 * g + 3] * inv)};
    *(bf16x4*)&Ob[32 + 8 * g + 4 * hi] = u1;
  }
}

// ---------------- launch ----------------
extern "C" void kernel_launch(void* const* d_in, const int* in_sizes, int n_in,
                              void* d_out, int out_size, void* d_ws, size_t ws_size,
                              hipStream_t stream) {
  const float* Xq   = (const float*)d_in[0];
  const float* Xkv  = (const float*)d_in[1];
  const float* Wq   = (const float*)d_in[2];
  const float* Wk   = (const float*)d_in[3];
  const float* Wv   = (const float*)d_in[4];
  const float* Wo   = (const float*)d_in[5];
  const float* relb = (const float*)d_in[6];
  float* out = (float*)d_out;

  char* ws = (char*)d_ws;
  const size_t SZ_X = (size_t)M_ * D_ * 2;   // 16 MB
  const size_t SZ_W = (size_t)D_ * D_ * 2;   // 2 MB
  bf16* Xq_b  = (bf16*)(ws);
  bf16* Xkv_b = (bf16*)(ws + SZ_X);
  bf16* Wq_t  = (bf16*)(ws + 2 * SZ_X);
  bf16* Wk_t  = (bf16*)(ws + 2 * SZ_X + SZ_W);
  bf16* Wv_t  = (bf16*)(ws + 2 * SZ_X + 2 * SZ_W);
  bf16* Wo_t  = (bf16*)(ws + 2 * SZ_X + 3 * SZ_W);
  bf16* Qb    = (bf16*)(ws + 2 * SZ_X + 4 * SZ_W);
  bf16* Kbuf  = (bf16*)(ws + 3 * SZ_X + 4 * SZ_W);
  bf16* Vt    = (bf16*)(ws + 4 * SZ_X + 4 * SZ_W);
  bf16* Ab    = (bf16*)(ws + 5 * SZ_X + 4 * SZ_W);
  float* tab  = (float*)(ws + 6 * SZ_X + 4 * SZ_W);  // 16*4096 f32

  cast2_kernel<<<16384, 256, 0, stream>>>(Xq, Xkv, Xq_b, Xkv_b);
  transpose_cast4_kernel<<<dim3(32, 32, 4), dim3(32, 8), 0, stream>>>(
      Wq, Wk, Wv, Wo, Wq_t, Wk_t, Wv_t, Wo_t);
  bias_table_kernel<<<256, 256, 0, stream>>>(relb, tab);

  proj_gemm_kernel<<<dim3(8, 64, 3), 256, 0, stream>>>(
      Xq_b, Xkv_b, Wq_t, Wk_t, Wv_t, Qb, Kbuf, Vt);
  attn_kernel<<<1024, 256, 0, stream>>>(Qb, Kbuf, Vt, tab, Ab);
  gemm_out_kernel<<<dim3(8, 64), 256, 0, stream>>>(Ab, Wo_t, out);
}

// Round 15
// 221.224 us; speedup vs baseline: 1.0809x; 1.0312x over previous
//
#include <hip/hip_runtime.h>
#include <hip/hip_bf16.h>
#include <math.h>

typedef __bf16 bf16;
typedef __attribute__((ext_vector_type(8))) __bf16 bf16x8;
typedef __attribute__((ext_vector_type(4))) __bf16 bf16x4;
typedef __attribute__((ext_vector_type(4))) float f32x4;
typedef __attribute__((ext_vector_type(16))) float f32x16;
typedef __attribute__((ext_vector_type(4), aligned(4))) float f32x4u;  // unaligned vec load

#define B_  4
#define S_  2048
#define D_  1024
#define H_  16
#define DH_ 64
#define M_  (B_ * S_)   // 8192
#define LOG2E 1.44269504088896f

static __device__ __forceinline__ f32x4 mfma16(bf16x8 a, bf16x8 b, f32x4 c) {
  return __builtin_amdgcn_mfma_f32_16x16x32_bf16(a, b, c, 0, 0, 0);
}
static __device__ __forceinline__ f32x16 mfma32(bf16x8 a, bf16x8 b, f32x16 c) {
  return __builtin_amdgcn_mfma_f32_32x32x16_bf16(a, b, c, 0, 0, 0);
}

static __device__ __forceinline__ void gld_lds16(const bf16* g, bf16* l) {
  __builtin_amdgcn_global_load_lds(
      (const __attribute__((address_space(1))) void*)g,
      (__attribute__((address_space(3))) void*)l, 16, 0, 0);
}

static __device__ __forceinline__ unsigned pkbf(float a, float b) {
  union { struct { __bf16 lo, hi; } s; unsigned u; } x;
  x.s.lo = (bf16)a; x.s.hi = (bf16)b;
  return x.u;
}

// ---------------- f32 -> bf16 cast, both inputs in one dispatch ----------------
__global__ __launch_bounds__(256)
void cast2_kernel(const float* __restrict__ a, const float* __restrict__ bsrc,
                  bf16* __restrict__ oa, bf16* __restrict__ ob) {
  const int blk = blockIdx.x;
  const float* in = (blk < 8192) ? a : bsrc;
  bf16* out = (blk < 8192) ? oa : ob;
  size_t i = ((size_t)(blk & 8191) * 256 + threadIdx.x) * 4;
  float4 v = *(const float4*)(in + i);
  bf16x4 o = {(bf16)v.x, (bf16)v.y, (bf16)v.z, (bf16)v.w};
  *(bf16x4*)(out + i) = o;
}

// ---------------- transpose+cast all 4 weights: out[n][k] = bf16(in[k][n]) ----------------
__global__ __launch_bounds__(256)
void transpose_cast4_kernel(const float* __restrict__ w0, const float* __restrict__ w1,
                            const float* __restrict__ w2, const float* __restrict__ w3,
                            bf16* __restrict__ o0, bf16* __restrict__ o1,
                            bf16* __restrict__ o2, bf16* __restrict__ o3) {
  __shared__ float tile[32][33];
  const int z = blockIdx.z;
  const float* in = (z == 0) ? w0 : (z == 1) ? w1 : (z == 2) ? w2 : w3;
  bf16* out = (z == 0) ? o0 : (z == 1) ? o1 : (z == 2) ? o2 : o3;
  int n0 = blockIdx.x * 32, k0 = blockIdx.y * 32;
  int tx = threadIdx.x, ty = threadIdx.y;
#pragma unroll
  for (int j = 0; j < 32; j += 8)
    tile[ty + j][tx] = in[(size_t)(k0 + ty + j) * D_ + n0 + tx];
  __syncthreads();
#pragma unroll
  for (int j = 0; j < 32; j += 8)
    out[(size_t)(n0 + ty + j) * D_ + k0 + tx] = (bf16)tile[tx][ty + j];
}

// ---------------- bias table (exp2 domain, fixed-max fold): tab = bias*log2e - 64 ----------------
__global__ __launch_bounds__(256)
void bias_table_kernel(const float* __restrict__ rel_bias, float* __restrict__ tab) {
  int i = blockIdx.x * 256 + threadIdx.x;   // 16*4096 entries
  int h = i >> 12, dp = i & 4095;
  int rel = dp - 2047;                       // rel = s - t
  int bucket = (rel > 0) ? 16 : 0;
  int rp = rel < 0 ? -rel : rel;
  if (rp < 8) {
    bucket += rp;
  } else {
    // ln(rp/8)/ln(16)*8 == 2*log2(rp/8); exact at rp = 16,32,64,128 boundaries
    int large = 8 + (int)(2.0f * __log2f((float)rp * 0.125f));
    bucket += (large < 15 ? large : 15);
  }
  tab[i] = rel_bias[bucket * H_ + h] * LOG2E - 64.0f;   // fixed max M=64 folded in
}

// ---------------- fused Q/K/V projection GEMMs (z = 0,1,2), BK=64, swizzled LDS ----------
// Staging: thread tid stages rows (tid>>3)+{0,32,64,96}, source col chunk
// ((tid&7)^((tid>>3)&7))*8 elems -> linear LDS dst (rule #21 pre-swizzled source).
// Reads XOR the 16B slot with (lrow&7)<<4 -> 16-way conflict becomes 2-way (free).
__global__ __launch_bounds__(256)
void proj_gemm_kernel(const bf16* __restrict__ Xq, const bf16* __restrict__ Xkv,
                      const bf16* __restrict__ Wq, const bf16* __restrict__ Wk,
                      const bf16* __restrict__ Wv,
                      bf16* __restrict__ Qb, bf16* __restrict__ Kb, bf16* __restrict__ Vt) {
  const int K = D_;
  __shared__ bf16 As[128][64];
  __shared__ bf16 Bs[128][64];
  const int z = blockIdx.z;
  const bf16* A  = (z == 0) ? Xq : Xkv;
  const bf16* Bt = (z == 0) ? Wq : (z == 1) ? Wk : Wv;
  const int tid = threadIdx.x;
  const int brow = blockIdx.y * 128, bcol = blockIdx.x * 128;
  const int wave = tid >> 6, lane = tid & 63;
  const int wr = (wave >> 1) * 64, wc = (wave & 1) * 64;
  const int lrow = lane & 15, lgrp = lane >> 4;

  f32x4 acc[4][4] = {};

  const int srow8 = tid >> 3;                               // 0..31
  const int scol = ((tid & 7) ^ (srow8 & 7)) * 8;           // pre-swizzled source chunk
  const bf16* ag = A + (size_t)(brow + srow8) * K + scol;
  const bf16* bg = Bt + (size_t)(bcol + srow8) * K + scol;
  const size_t r32 = (size_t)32 * K;                        // row+32k keeps row&7
  bf16* al = &As[0][0] + tid * 8;
  bf16* bl = &Bs[0][0] + tid * 8;

  const int rsw = (lrow & 7) << 4;                          // read-side byte XOR
  const char* arp = (const char*)&As[0][0];
  const char* brp = (const char*)&Bs[0][0];

  for (int k0 = 0; k0 < K; k0 += 64) {
    __syncthreads();
    gld_lds16(ag + k0,           al);
    gld_lds16(ag + k0 + r32,     al + 2048);
    gld_lds16(ag + k0 + 2 * r32, al + 4096);
    gld_lds16(ag + k0 + 3 * r32, al + 6144);
    gld_lds16(bg + k0,           bl);
    gld_lds16(bg + k0 + r32,     bl + 2048);
    gld_lds16(bg + k0 + 2 * r32, bl + 4096);
    gld_lds16(bg + k0 + 3 * r32, bl + 6144);
    __syncthreads();
#pragma unroll
    for (int kk = 0; kk < 2; ++kk) {
      bf16x8 af[4], bfr[4];
#pragma unroll
      for (int i = 0; i < 4; ++i) {
        af[i]  = *(const bf16x8*)(arp + (wr + i * 16 + lrow) * 128 +
                                  ((kk * 64 + (lgrp << 4)) ^ rsw));
        bfr[i] = *(const bf16x8*)(brp + (wc + i * 16 + lrow) * 128 +
                                  ((kk * 64 + (lgrp << 4)) ^ rsw));
      }
#pragma unroll
      for (int mi = 0; mi < 4; ++mi)
#pragma unroll
        for (int ni = 0; ni < 4; ++ni)
          acc[mi][ni] = mfma16(af[mi], bfr[ni], acc[mi][ni]);
    }
  }

  const float scl = (z == 0) ? LOG2E : 1.0f;
#pragma unroll
  for (int mi = 0; mi < 4; ++mi) {
    const int rowb = brow + wr + mi * 16 + lgrp * 4;
#pragma unroll
    for (int ni = 0; ni < 4; ++ni) {
      const int col = bcol + wc + ni * 16 + lrow;
      const int hh = col >> 6, d = col & (DH_ - 1);
      if (z == 2) {
        // V^T store: rows r are consecutive s at fixed d -> one 8B store
        const int bb = rowb >> 11, s = rowb & (S_ - 1);
        bf16x4 pk = {(bf16)acc[mi][ni][0], (bf16)acc[mi][ni][1],
                     (bf16)acc[mi][ni][2], (bf16)acc[mi][ni][3]};
        *(bf16x4*)&Vt[((size_t)((bb * H_ + hh) * DH_ + d)) * S_ + s] = pk;
      } else {
#pragma unroll
        for (int r = 0; r < 4; ++r) {
          const float v = acc[mi][ni][r] * scl;
          const int m = rowb + r;
          const int bb = m >> 11, s = m & (S_ - 1);
          if (z == 0)
            Qb[((size_t)((bb * H_ + hh) * S_ + s)) * DH_ + d] = (bf16)v;
          else
            Kb[((size_t)((bb * H_ + hh) * S_ + s)) * DH_ + d] = (bf16)v;
        }
      }
    }
  }
}

// ---------------- output GEMM: out[MxN] f32 = Ab * Wo_t^T, BK=64 swizzled ----------------
__global__ __launch_bounds__(256)
void gemm_out_kernel(const bf16* __restrict__ A, const bf16* __restrict__ Bt,
                     float* __restrict__ Cout) {
  const int K = D_, N = D_;
  __shared__ bf16 As[128][64];
  __shared__ bf16 Bs[128][64];
  const int tid = threadIdx.x;
  const int brow = blockIdx.y * 128, bcol = blockIdx.x * 128;
  const int wave = tid >> 6, lane = tid & 63;
  const int wr = (wave >> 1) * 64, wc = (wave & 1) * 64;
  const int lrow = lane & 15, lgrp = lane >> 4;

  f32x4 acc[4][4] = {};

  const int srow8 = tid >> 3;
  const int scol = ((tid & 7) ^ (srow8 & 7)) * 8;
  const bf16* ag = A + (size_t)(brow + srow8) * K + scol;
  const bf16* bg = Bt + (size_t)(bcol + srow8) * K + scol;
  const size_t r32 = (size_t)32 * K;
  bf16* al = &As[0][0] + tid * 8;
  bf16* bl = &Bs[0][0] + tid * 8;

  const int rsw = (lrow & 7) << 4;
  const char* arp = (const char*)&As[0][0];
  const char* brp = (const char*)&Bs[0][0];

  for (int k0 = 0; k0 < K; k0 += 64) {
    __syncthreads();
    gld_lds16(ag + k0,           al);
    gld_lds16(ag + k0 + r32,     al + 2048);
    gld_lds16(ag + k0 + 2 * r32, al + 4096);
    gld_lds16(ag + k0 + 3 * r32, al + 6144);
    gld_lds16(bg + k0,           bl);
    gld_lds16(bg + k0 + r32,     bl + 2048);
    gld_lds16(bg + k0 + 2 * r32, bl + 4096);
    gld_lds16(bg + k0 + 3 * r32, bl + 6144);
    __syncthreads();
#pragma unroll
    for (int kk = 0; kk < 2; ++kk) {
      bf16x8 af[4], bfr[4];
#pragma unroll
      for (int i = 0; i < 4; ++i) {
        af[i]  = *(const bf16x8*)(arp + (wr + i * 16 + lrow) * 128 +
                                  ((kk * 64 + (lgrp << 4)) ^ rsw));
        bfr[i] = *(const bf16x8*)(brp + (wc + i * 16 + lrow) * 128 +
                                  ((kk * 64 + (lgrp << 4)) ^ rsw));
      }
#pragma unroll
      for (int mi = 0; mi < 4; ++mi)
#pragma unroll
        for (int ni = 0; ni < 4; ++ni)
          acc[mi][ni] = mfma16(af[mi], bfr[ni], acc[mi][ni]);
    }
  }

#pragma unroll
  for (int mi = 0; mi < 4; ++mi) {
    const int rowb = brow + wr + mi * 16 + lgrp * 4;
#pragma unroll
    for (int ni = 0; ni < 4; ++ni) {
      const int col = bcol + wc + ni * 16 + lrow;
#pragma unroll
      for (int r = 0; r < 4; ++r)
        Cout[(size_t)(rowb + r) * N + col] = acc[mi][ni][r];
    }
  }
}

// ---------------- flash attention v7 (verbatim round-12 known-good, untouched) ----------
// 1024 blocks (XCD-swizzled), 256 thr = 4 waves; lane owns 1 q-row.
// Single LDS arena: K0[0,8K) K1[8K,16K) V0[16K,24K) V1[24K,32K).
__global__ __launch_bounds__(256, 4)
void attn_kernel(const bf16* __restrict__ Q, const bf16* __restrict__ Kb,
                 const bf16* __restrict__ Vt, const float* __restrict__ tab,
                 bf16* __restrict__ Oa) {
  __shared__ bf16 SB[4][4096];   // 8KB regions: K0,K1,V0,V1; 32 rows x 256B, swizzled

  const int bid = blockIdx.x;
  const int w = ((bid & 7) << 7) + (bid >> 3);   // XCD chunk of 128 = 8 full (b,h) panels
  const int qt = w & 15, h = (w >> 4) & 15, b = w >> 8;
  const int tid = threadIdx.x;
  const int wave = tid >> 6, lane = tid & 63;
  const int l31 = lane & 31;
  const int hi = lane >> 5;       // 0/1
  const int t = qt * 128 + wave * 32 + l31;   // this lane's q-row

  const bf16* Qp = Q + (size_t)(b * H_ + h) * S_ * DH_;
  const bf16* Kp = Kb + (size_t)(b * H_ + h) * S_ * DH_;
  const bf16* Vp = Vt + (size_t)(b * H_ + h) * DH_ * S_;
  const float* btb = tab + h * 4096 + 2047 - t;

  // ---- staging: thread stages dst bytes tid*16 (+4096) per 8KB region
  const int row0 = tid >> 4, row1 = row0 + 16;
  const int colS = (tid & 15) << 4;
  const int col0 = colS ^ ((row0 & 15) << 4);
  const int col1 = colS ^ ((row1 & 15) << 4);
  const bf16* ks0 = Kp + (size_t)(row0 + 32 * (col0 >> 7)) * DH_ + ((col0 & 127) >> 1);
  const bf16* ks1 = Kp + (size_t)(row1 + 32 * (col1 >> 7)) * DH_ + ((col1 & 127) >> 1);
  const bf16* vs0 = Vp + (size_t)(row0 + 32 * (col0 >> 7)) * S_ + ((col0 & 127) >> 1);
  const bf16* vs1 = Vp + (size_t)(row1 + 32 * (col1 >> 7)) * S_ + ((col1 & 127) >> 1);
  bf16* sd = &SB[0][0] + tid * 8;   // + {0,2048} elems within region, + region*4096

  // ---- precomputed LDS read pointers: ra[c][sub]; buf/V via literal offsets
  const int swz = (l31 & 15) << 4;
  const char* rb = (const char*)&SB[0][0] + l31 * 256;
  const char* ra[4][2];
#pragma unroll
  for (int c = 0; c < 4; ++c)
#pragma unroll
    for (int sub = 0; sub < 2; ++sub)
      ra[c][sub] = rb + ((c * 32 + hi * 16 + sub * 128) ^ swz);

  // ---- Q fragments (B-operand): B[row=q=lane&31][k = hi*8+j], per d-chunk c (K=16)
  bf16x8 qf[4];
#pragma unroll
  for (int c = 0; c < 4; ++c)
    qf[c] = *(const bf16x8*)&Qp[(size_t)t * DH_ + c * 16 + hi * 8];

  float l_r = 0.f;
  f32x16 o0 = {}, o1 = {};   // PV accum: d 0..31 / 32..63, q = lane&31 (col)

  // prologue: stage tile 0 into buf 0
  gld_lds16(ks0, sd); gld_lds16(ks1, sd + 2048);
  gld_lds16(vs0, sd + 8192); gld_lds16(vs1, sd + 10240);
  __syncthreads();

  // one KV tile; BUF is a literal so every ds_read offset is an immediate
#define ATTN_TILE(BUF, S0)                                                        \
  {                                                                               \
    if ((S0) + 64 < S_) {                                                         \
      const int nb = (BUF) ^ 1;                                                   \
      gld_lds16(ks0 + (size_t)((S0) + 64) * DH_, sd + nb * 4096);                 \
      gld_lds16(ks1 + (size_t)((S0) + 64) * DH_, sd + nb * 4096 + 2048);          \
      gld_lds16(vs0 + ((S0) + 64), sd + nb * 4096 + 8192);                        \
      gld_lds16(vs1 + ((S0) + 64), sd + nb * 4096 + 10240);                       \
    }                                                                             \
    f32x16 sc0, sc1;                                                              \
    _Pragma("unroll")                                                             \
    for (int g = 0; g < 4; ++g) {                                                 \
      f32x4u b0 = *(const f32x4u*)(btb + (S0) + 8 * g + 4 * hi);                  \
      f32x4u b1 = *(const f32x4u*)(btb + (S0) + 32 + 8 * g + 4 * hi);             \
      _Pragma("unroll")                                                           \
      for (int v = 0; v < 4; ++v) { sc0[4 * g + v] = b0[v]; sc1[4 * g + v] = b1[v]; } \
    }                                                                             \
    _Pragma("unroll")                                                             \
    for (int c = 0; c < 4; ++c) {                                                 \
      bf16x8 k0 = *(const bf16x8*)(ra[c][0] + (BUF) * 8192);                      \
      bf16x8 k1 = *(const bf16x8*)(ra[c][1] + (BUF) * 8192);                      \
      sc0 = mfma32(k0, qf[c], sc0);                                               \
      sc1 = mfma32(k1, qf[c], sc1);                                               \
    }                                                                             \
    unsigned pw[16];                                                              \
    float q0s = 0.f, q1s = 0.f, q2s = 0.f, q3s = 0.f;                             \
    _Pragma("unroll")                                                             \
    for (int r2 = 0; r2 < 8; ++r2) {                                              \
      float a0 = __builtin_amdgcn_exp2f(sc0[2 * r2]);                             \
      float a1 = __builtin_amdgcn_exp2f(sc0[2 * r2 + 1]);                         \
      float c0 = __builtin_amdgcn_exp2f(sc1[2 * r2]);                             \
      float c1 = __builtin_amdgcn_exp2f(sc1[2 * r2 + 1]);                         \
      q0s += a0; q1s += a1; q2s += c0; q3s += c1;                                 \
      pw[r2] = pkbf(a0, a1);                                                      \
      pw[8 + r2] = pkbf(c0, c1);                                                  \
    }                                                                             \
    l_r += (q0s + q1s) + (q2s + q3s);                                             \
    /* all 8 cross-half exchanges upfront (overlapping lgkm waits) */             \
    unsigned sh[8];                                                               \
    _Pragma("unroll")                                                             \
    for (int g = 0; g < 4; ++g) {                                                 \
      const int base = (g & 1) * 4 + (g >> 1) * 8;                                \
      sh[2 * g]     = __shfl_xor(hi ? pw[base + 0] : pw[base + 2], 32);           \
      sh[2 * g + 1] = __shfl_xor(hi ? pw[base + 1] : pw[base + 3], 32);           \
    }                                                                             \
    _Pragma("unroll")                                                             \
    for (int g = 0; g < 4; ++g) {                                                 \
      const int base = (g & 1) * 4 + (g >> 1) * 8;                                \
      int4 bi = { (int)(hi ? sh[2 * g]     : pw[base + 0]),                       \
                  (int)(hi ? sh[2 * g + 1] : pw[base + 1]),                       \
                  (int)(hi ? pw[base + 2] : sh[2 * g]),                           \
                  (int)(hi ? pw[base + 3] : sh[2 * g + 1]) };                     \
      bf16x8 pb = *(bf16x8*)&bi;                                                  \
      bf16x8 v0 = *(const bf16x8*)(ra[g][0] + 16384 + (BUF) * 8192);              \
      bf16x8 v1 = *(const bf16x8*)(ra[g][1] + 16384 + (BUF) * 8192);              \
      o0 = mfma32(v0, pb, o0);                                                    \
      o1 = mfma32(v1, pb, o1);                                                    \
    }                                                                             \
    __syncthreads();                                                              \
  }

  for (int s0 = 0; s0 < S_; s0 += 128) {
    ATTN_TILE(0, s0)
    ATTN_TILE(1, s0 + 64)
  }
#undef ATTN_TILE

  // ---- finalize: one shuffle for the full row-sum; per-lane scalar normalize
  l_r += __shfl_xor(l_r, 32);
  const float inv = 1.0f / l_r;
  bf16* Ob = Oa + ((size_t)(b * S_ + t)) * D_ + h * DH_;
#pragma unroll
  for (int g = 0; g < 4; ++g) {
    bf16x4 u0 = {(bf16)(o0[4 * g + 0] * inv), (bf16)(o0[4 * g + 1] * inv),
                 (bf16)(o0[4 * g + 2] * inv), (bf16)(o0[4 * g + 3] * inv)};
    *(bf16x4*)&Ob[8 * g + 4 * hi] = u0;
    bf16x4 u1 = {(bf16)(o1[4 * g + 0] * inv), (bf16)(o1[4 * g + 1] * inv),
                 (bf16)(o1[4 * g + 2] * inv), (bf16)(o1[4 * g + 3] * inv)};
    *(bf16x4*)&Ob[32 + 8 * g + 4 * hi] = u1;
  }
}

// ---------------- launch ----------------
extern "C" void kernel_launch(void* const* d_in, const int* in_sizes, int n_in,
                              void* d_out, int out_size, void* d_ws, size_t ws_size,
                              hipStream_t stream) {
  const float* Xq   = (const float*)d_in[0];
  const float* Xkv  = (const float*)d_in[1];
  const float* Wq   = (const float*)d_in[2];
  const float* Wk   = (const float*)d_in[3];
  const float* Wv   = (const float*)d_in[4];
  const float* Wo   = (const float*)d_in[5];
  const float* relb = (const float*)d_in[6];
  float* out = (float*)d_out;

  char* ws = (char*)d_ws;
  const size_t SZ_X = (size_t)M_ * D_ * 2;   // 16 MB
  const size_t SZ_W = (size_t)D_ * D_ * 2;   // 2 MB
  bf16* Xq_b  = (bf16*)(ws);
  bf16* Xkv_b = (bf16*)(ws + SZ_X);
  bf16* Wq_t  = (bf16*)(ws + 2 * SZ_X);
  bf16* Wk_t  = (bf16*)(ws + 2 * SZ_X + SZ_W);
  bf16* Wv_t  = (bf16*)(ws + 2 * SZ_X + 2 * SZ_W);
  bf16* Wo_t  = (bf16*)(ws + 2 * SZ_X + 3 * SZ_W);
  bf16* Qb    = (bf16*)(ws + 2 * SZ_X + 4 * SZ_W);
  bf16* Kbuf  = (bf16*)(ws + 3 * SZ_X + 4 * SZ_W);
  bf16* Vt    = (bf16*)(ws + 4 * SZ_X + 4 * SZ_W);
  bf16* Ab    = (bf16*)(ws + 5 * SZ_X + 4 * SZ_W);
  float* tab  = (float*)(ws + 6 * SZ_X + 4 * SZ_W);  // 16*4096 f32

  cast2_kernel<<<16384, 256, 0, stream>>>(Xq, Xkv, Xq_b, Xkv_b);
  transpose_cast4_kernel<<<dim3(32, 32, 4), dim3(32, 8), 0, stream>>>(
      Wq, Wk, Wv, Wo, Wq_t, Wk_t, Wv_t, Wo_t);
  bias_table_kernel<<<256, 256, 0, stream>>>(relb, tab);

  proj_gemm_kernel<<<dim3(8, 64, 3), 256, 0, stream>>>(
      Xq_b, Xkv_b, Wq_t, Wk_t, Wv_t, Qb, Kbuf, Vt);
  attn_kernel<<<1024, 256, 0, stream>>>(Qb, Kbuf, Vt, tab, Ab);
  gemm_out_kernel<<<dim3(8, 64), 256, 0, stream>>>(Ab, Wo_t, out);
}

// Round 16
// 204.978 us; speedup vs baseline: 1.1665x; 1.0793x over previous
//
#include <hip/hip_runtime.h>
#include <hip/hip_bf16.h>
#include <math.h>

typedef __bf16 bf16;
typedef __attribute__((ext_vector_type(8))) __bf16 bf16x8;
typedef __attribute__((ext_vector_type(4))) __bf16 bf16x4;
typedef __attribute__((ext_vector_type(4))) float f32x4;
typedef __attribute__((ext_vector_type(16))) float f32x16;
typedef __attribute__((ext_vector_type(4), aligned(4))) float f32x4u;  // unaligned vec load

#define B_  4
#define S_  2048
#define D_  1024
#define H_  16
#define DH_ 64
#define M_  (B_ * S_)   // 8192
#define LOG2E 1.44269504088896f

static __device__ __forceinline__ f32x4 mfma16(bf16x8 a, bf16x8 b, f32x4 c) {
  return __builtin_amdgcn_mfma_f32_16x16x32_bf16(a, b, c, 0, 0, 0);
}
static __device__ __forceinline__ f32x16 mfma32(bf16x8 a, bf16x8 b, f32x16 c) {
  return __builtin_amdgcn_mfma_f32_32x32x16_bf16(a, b, c, 0, 0, 0);
}

static __device__ __forceinline__ void gld_lds16(const bf16* g, bf16* l) {
  __builtin_amdgcn_global_load_lds(
      (const __attribute__((address_space(1))) void*)g,
      (__attribute__((address_space(3))) void*)l, 16, 0, 0);
}

static __device__ __forceinline__ unsigned pkbf(float a, float b) {
  union { struct { __bf16 lo, hi; } s; unsigned u; } x;
  x.s.lo = (bf16)a; x.s.hi = (bf16)b;
  return x.u;
}

// ---------------- f32 -> bf16 cast, both inputs in one dispatch ----------------
__global__ __launch_bounds__(256)
void cast2_kernel(const float* __restrict__ a, const float* __restrict__ bsrc,
                  bf16* __restrict__ oa, bf16* __restrict__ ob) {
  const int blk = blockIdx.x;
  const float* in = (blk < 8192) ? a : bsrc;
  bf16* out = (blk < 8192) ? oa : ob;
  size_t i = ((size_t)(blk & 8191) * 256 + threadIdx.x) * 4;
  float4 v = *(const float4*)(in + i);
  bf16x4 o = {(bf16)v.x, (bf16)v.y, (bf16)v.z, (bf16)v.w};
  *(bf16x4*)(out + i) = o;
}

// ---------------- transpose+cast all 4 weights: out[n][k] = bf16(in[k][n]) ----------------
__global__ __launch_bounds__(256)
void transpose_cast4_kernel(const float* __restrict__ w0, const float* __restrict__ w1,
                            const float* __restrict__ w2, const float* __restrict__ w3,
                            bf16* __restrict__ o0, bf16* __restrict__ o1,
                            bf16* __restrict__ o2, bf16* __restrict__ o3) {
  __shared__ float tile[32][33];
  const int z = blockIdx.z;
  const float* in = (z == 0) ? w0 : (z == 1) ? w1 : (z == 2) ? w2 : w3;
  bf16* out = (z == 0) ? o0 : (z == 1) ? o1 : (z == 2) ? o2 : o3;
  int n0 = blockIdx.x * 32, k0 = blockIdx.y * 32;
  int tx = threadIdx.x, ty = threadIdx.y;
#pragma unroll
  for (int j = 0; j < 32; j += 8)
    tile[ty + j][tx] = in[(size_t)(k0 + ty + j) * D_ + n0 + tx];
  __syncthreads();
#pragma unroll
  for (int j = 0; j < 32; j += 8)
    out[(size_t)(n0 + ty + j) * D_ + k0 + tx] = (bf16)tile[tx][ty + j];
}

// ---------------- bias table (exp2 domain, fixed-max fold): tab = bias*log2e - 64 ----------------
__global__ __launch_bounds__(256)
void bias_table_kernel(const float* __restrict__ rel_bias, float* __restrict__ tab) {
  int i = blockIdx.x * 256 + threadIdx.x;   // 16*4096 entries
  int h = i >> 12, dp = i & 4095;
  int rel = dp - 2047;                       // rel = s - t
  int bucket = (rel > 0) ? 16 : 0;
  int rp = rel < 0 ? -rel : rel;
  if (rp < 8) {
    bucket += rp;
  } else {
    // ln(rp/8)/ln(16)*8 == 2*log2(rp/8); exact at rp = 16,32,64,128 boundaries
    int large = 8 + (int)(2.0f * __log2f((float)rp * 0.125f));
    bucket += (large < 15 ? large : 15);
  }
  tab[i] = rel_bias[bucket * H_ + h] * LOG2E - 64.0f;   // fixed max M=64 folded in
}

// ---------------- fused Q/K/V projection GEMMs, BK=64, swizzled LDS, XCD remap ----------
// 1D grid 1536; xcd=bid&7 owns a contiguous (y,z)-chunk with x fastest -> A-panel L2 reuse.
__global__ __launch_bounds__(256)
void proj_gemm_kernel(const bf16* __restrict__ Xq, const bf16* __restrict__ Xkv,
                      const bf16* __restrict__ Wq, const bf16* __restrict__ Wk,
                      const bf16* __restrict__ Wv,
                      bf16* __restrict__ Qb, bf16* __restrict__ Kb, bf16* __restrict__ Vt) {
  const int K = D_;
  __shared__ bf16 As[128][64];
  __shared__ bf16 Bs[128][64];
  // XCD-aware decode: bid = xcd + 8*(bx + 8*r), p = r + xcd*24, y = p%64, z = p/64
  const int bid = blockIdx.x;
  const int xcd = bid & 7, j = bid >> 3;
  const int bx = j & 7;
  const int p = (j >> 3) + xcd * 24;
  const int by = p & 63, z = p >> 6;
  const bf16* A  = (z == 0) ? Xq : Xkv;
  const bf16* Bt = (z == 0) ? Wq : (z == 1) ? Wk : Wv;
  const int tid = threadIdx.x;
  const int brow = by * 128, bcol = bx * 128;
  const int wave = tid >> 6, lane = tid & 63;
  const int wr = (wave >> 1) * 64, wc = (wave & 1) * 64;
  const int lrow = lane & 15, lgrp = lane >> 4;

  f32x4 acc[4][4] = {};

  const int srow8 = tid >> 3;                               // 0..31
  const int scol = ((tid & 7) ^ (srow8 & 7)) * 8;           // pre-swizzled source chunk
  const bf16* ag = A + (size_t)(brow + srow8) * K + scol;
  const bf16* bg = Bt + (size_t)(bcol + srow8) * K + scol;
  const size_t r32 = (size_t)32 * K;                        // row+32k keeps row&7
  bf16* al = &As[0][0] + tid * 8;
  bf16* bl = &Bs[0][0] + tid * 8;

  const int rsw = (lrow & 7) << 4;                          // read-side byte XOR
  const char* arp = (const char*)&As[0][0];
  const char* brp = (const char*)&Bs[0][0];

  for (int k0 = 0; k0 < K; k0 += 64) {
    __syncthreads();
    gld_lds16(ag + k0,           al);
    gld_lds16(ag + k0 + r32,     al + 2048);
    gld_lds16(ag + k0 + 2 * r32, al + 4096);
    gld_lds16(ag + k0 + 3 * r32, al + 6144);
    gld_lds16(bg + k0,           bl);
    gld_lds16(bg + k0 + r32,     bl + 2048);
    gld_lds16(bg + k0 + 2 * r32, bl + 4096);
    gld_lds16(bg + k0 + 3 * r32, bl + 6144);
    __syncthreads();
#pragma unroll
    for (int kk = 0; kk < 2; ++kk) {
      bf16x8 af[4], bfr[4];
#pragma unroll
      for (int i = 0; i < 4; ++i) {
        af[i]  = *(const bf16x8*)(arp + (wr + i * 16 + lrow) * 128 +
                                  ((kk * 64 + (lgrp << 4)) ^ rsw));
        bfr[i] = *(const bf16x8*)(brp + (wc + i * 16 + lrow) * 128 +
                                  ((kk * 64 + (lgrp << 4)) ^ rsw));
      }
#pragma unroll
      for (int mi = 0; mi < 4; ++mi)
#pragma unroll
        for (int ni = 0; ni < 4; ++ni)
          acc[mi][ni] = mfma16(af[mi], bfr[ni], acc[mi][ni]);
    }
  }

  const float scl = (z == 0) ? LOG2E : 1.0f;
#pragma unroll
  for (int mi = 0; mi < 4; ++mi) {
    const int rowb = brow + wr + mi * 16 + lgrp * 4;
#pragma unroll
    for (int ni = 0; ni < 4; ++ni) {
      const int col = bcol + wc + ni * 16 + lrow;
      const int hh = col >> 6, d = col & (DH_ - 1);
      if (z == 2) {
        // V^T store: rows r are consecutive s at fixed d -> one 8B store
        const int bb = rowb >> 11, s = rowb & (S_ - 1);
        bf16x4 pk = {(bf16)acc[mi][ni][0], (bf16)acc[mi][ni][1],
                     (bf16)acc[mi][ni][2], (bf16)acc[mi][ni][3]};
        *(bf16x4*)&Vt[((size_t)((bb * H_ + hh) * DH_ + d)) * S_ + s] = pk;
      } else {
#pragma unroll
        for (int r = 0; r < 4; ++r) {
          const float v = acc[mi][ni][r] * scl;
          const int m = rowb + r;
          const int bb = m >> 11, s = m & (S_ - 1);
          if (z == 0)
            Qb[((size_t)((bb * H_ + hh) * S_ + s)) * DH_ + d] = (bf16)v;
          else
            Kb[((size_t)((bb * H_ + hh) * S_ + s)) * DH_ + d] = (bf16)v;
        }
      }
    }
  }
}

// ---------------- output GEMM: out f32 = Ab * Wo_t^T, BK=64 swizzled, XCD remap --------
__global__ __launch_bounds__(256)
void gemm_out_kernel(const bf16* __restrict__ A, const bf16* __restrict__ Bt,
                     float* __restrict__ Cout) {
  const int K = D_, N = D_;
  __shared__ bf16 As[128][64];
  __shared__ bf16 Bs[128][64];
  // XCD-aware decode: 512 blocks; xcd gets 8 y-panels x all 8 x
  const int bid = blockIdx.x;
  const int xcd = bid & 7, j = bid >> 3;
  const int bx = j & 7;
  const int by = (j >> 3) + xcd * 8;
  const int tid = threadIdx.x;
  const int brow = by * 128, bcol = bx * 128;
  const int wave = tid >> 6, lane = tid & 63;
  const int wr = (wave >> 1) * 64, wc = (wave & 1) * 64;
  const int lrow = lane & 15, lgrp = lane >> 4;

  f32x4 acc[4][4] = {};

  const int srow8 = tid >> 3;
  const int scol = ((tid & 7) ^ (srow8 & 7)) * 8;
  const bf16* ag = A + (size_t)(brow + srow8) * K + scol;
  const bf16* bg = Bt + (size_t)(bcol + srow8) * K + scol;
  const size_t r32 = (size_t)32 * K;
  bf16* al = &As[0][0] + tid * 8;
  bf16* bl = &Bs[0][0] + tid * 8;

  const int rsw = (lrow & 7) << 4;
  const char* arp = (const char*)&As[0][0];
  const char* brp = (const char*)&Bs[0][0];

  for (int k0 = 0; k0 < K; k0 += 64) {
    __syncthreads();
    gld_lds16(ag + k0,           al);
    gld_lds16(ag + k0 + r32,     al + 2048);
    gld_lds16(ag + k0 + 2 * r32, al + 4096);
    gld_lds16(ag + k0 + 3 * r32, al + 6144);
    gld_lds16(bg + k0,           bl);
    gld_lds16(bg + k0 + r32,     bl + 2048);
    gld_lds16(bg + k0 + 2 * r32, bl + 4096);
    gld_lds16(bg + k0 + 3 * r32, bl + 6144);
    __syncthreads();
#pragma unroll
    for (int kk = 0; kk < 2; ++kk) {
      bf16x8 af[4], bfr[4];
#pragma unroll
      for (int i = 0; i < 4; ++i) {
        af[i]  = *(const bf16x8*)(arp + (wr + i * 16 + lrow) * 128 +
                                  ((kk * 64 + (lgrp << 4)) ^ rsw));
        bfr[i] = *(const bf16x8*)(brp + (wc + i * 16 + lrow) * 128 +
                                  ((kk * 64 + (lgrp << 4)) ^ rsw));
      }
#pragma unroll
      for (int mi = 0; mi < 4; ++mi)
#pragma unroll
        for (int ni = 0; ni < 4; ++ni)
          acc[mi][ni] = mfma16(af[mi], bfr[ni], acc[mi][ni]);
    }
  }

#pragma unroll
  for (int mi = 0; mi < 4; ++mi) {
    const int rowb = brow + wr + mi * 16 + lgrp * 4;
#pragma unroll
    for (int ni = 0; ni < 4; ++ni) {
      const int col = bcol + wc + ni * 16 + lrow;
#pragma unroll
      for (int r = 0; r < 4; ++r)
        Cout[(size_t)(rowb + r) * N + col] = acc[mi][ni][r];
    }
  }
}

// ---------------- flash attention v11: QBLK=256, 512 thr = 8 waves; body = v7 verbatim ----
// 512 blocks (XCD-swizzled: 8 full (b,h) panels per XCD), lane owns 1 q-row.
// Single LDS arena: K0[0,8K) K1[8K,16K) V0[16K,24K) V1[24K,32K).
__global__ __launch_bounds__(512, 4)
void attn_kernel(const bf16* __restrict__ Q, const bf16* __restrict__ Kb,
                 const bf16* __restrict__ Vt, const float* __restrict__ tab,
                 bf16* __restrict__ Oa) {
  __shared__ bf16 SB[4][4096];   // 8KB regions: K0,K1,V0,V1; 32 rows x 256B, swizzled

  const int bid = blockIdx.x;
  const int w = ((bid & 7) << 6) + (bid >> 3);   // XCD chunk of 64 = 8 full (b,h) panels
  const int qt = w & 7, h = (w >> 3) & 15, b = w >> 7;
  const int tid = threadIdx.x;
  const int wave = tid >> 6, lane = tid & 63;
  const int l31 = lane & 31;
  const int hi = lane >> 5;       // 0/1
  const int t = qt * 256 + wave * 32 + l31;   // this lane's q-row

  const bf16* Qp = Q + (size_t)(b * H_ + h) * S_ * DH_;
  const bf16* Kp = Kb + (size_t)(b * H_ + h) * S_ * DH_;
  const bf16* Vp = Vt + (size_t)(b * H_ + h) * DH_ * S_;
  const float* btb = tab + h * 4096 + 2047 - t;

  // ---- staging: 512 threads cover one 8KB region per call; dst bytes tid*16
  const int srow = tid >> 4;                       // 0..31
  const int colS = (tid & 15) << 4;
  const int scol = colS ^ ((srow & 15) << 4);
  const bf16* ks0 = Kp + (size_t)(srow + 32 * (scol >> 7)) * DH_ + ((scol & 127) >> 1);
  const bf16* vs0 = Vp + (size_t)(srow + 32 * (scol >> 7)) * S_ + ((scol & 127) >> 1);
  bf16* sd = &SB[0][0] + tid * 8;   // + buf*4096 (K) / +8192 (V regions)

  // ---- precomputed LDS read pointers: ra[c][sub]; buf/V via literal offsets
  const int swz = (l31 & 15) << 4;
  const char* rb = (const char*)&SB[0][0] + l31 * 256;
  const char* ra[4][2];
#pragma unroll
  for (int c = 0; c < 4; ++c)
#pragma unroll
    for (int sub = 0; sub < 2; ++sub)
      ra[c][sub] = rb + ((c * 32 + hi * 16 + sub * 128) ^ swz);

  // ---- Q fragments (B-operand): B[row=q=lane&31][k = hi*8+j], per d-chunk c (K=16)
  bf16x8 qf[4];
#pragma unroll
  for (int c = 0; c < 4; ++c)
    qf[c] = *(const bf16x8*)&Qp[(size_t)t * DH_ + c * 16 + hi * 8];

  float l_r = 0.f;
  f32x16 o0 = {}, o1 = {};   // PV accum: d 0..31 / 32..63, q = lane&31 (col)

  // prologue: stage tile 0 into buf 0
  gld_lds16(ks0, sd);
  gld_lds16(vs0, sd + 8192);
  __syncthreads();

  // one KV tile; BUF is a literal so every ds_read offset is an immediate
#define ATTN_TILE(BUF, S0)                                                        \
  {                                                                               \
    if ((S0) + 64 < S_) {                                                         \
      const int nb = (BUF) ^ 1;                                                   \
      gld_lds16(ks0 + (size_t)((S0) + 64) * DH_, sd + nb * 4096);                 \
      gld_lds16(vs0 + ((S0) + 64), sd + nb * 4096 + 8192);                        \
    }                                                                             \
    f32x16 sc0, sc1;                                                              \
    _Pragma("unroll")                                                             \
    for (int g = 0; g < 4; ++g) {                                                 \
      f32x4u b0 = *(const f32x4u*)(btb + (S0) + 8 * g + 4 * hi);                  \
      f32x4u b1 = *(const f32x4u*)(btb + (S0) + 32 + 8 * g + 4 * hi);             \
      _Pragma("unroll")                                                           \
      for (int v = 0; v < 4; ++v) { sc0[4 * g + v] = b0[v]; sc1[4 * g + v] = b1[v]; } \
    }                                                                             \
    _Pragma("unroll")                                                             \
    for (int c = 0; c < 4; ++c) {                                                 \
      bf16x8 k0 = *(const bf16x8*)(ra[c][0] + (BUF) * 8192);                      \
      bf16x8 k1 = *(const bf16x8*)(ra[c][1] + (BUF) * 8192);                      \
      sc0 = mfma32(k0, qf[c], sc0);                                               \
      sc1 = mfma32(k1, qf[c], sc1);                                               \
    }                                                                             \
    unsigned pw[16];                                                              \
    float q0s = 0.f, q1s = 0.f, q2s = 0.f, q3s = 0.f;                             \
    _Pragma("unroll")                                                             \
    for (int r2 = 0; r2 < 8; ++r2) {                                              \
      float a0 = __builtin_amdgcn_exp2f(sc0[2 * r2]);                             \
      float a1 = __builtin_amdgcn_exp2f(sc0[2 * r2 + 1]);                         \
      float c0 = __builtin_amdgcn_exp2f(sc1[2 * r2]);                             \
      float c1 = __builtin_amdgcn_exp2f(sc1[2 * r2 + 1]);                         \
      q0s += a0; q1s += a1; q2s += c0; q3s += c1;                                 \
      pw[r2] = pkbf(a0, a1);                                                      \
      pw[8 + r2] = pkbf(c0, c1);                                                  \
    }                                                                             \
    l_r += (q0s + q1s) + (q2s + q3s);                                             \
    /* all 8 cross-half exchanges upfront (overlapping lgkm waits) */             \
    unsigned sh[8];                                                               \
    _Pragma("unroll")                                                             \
    for (int g = 0; g < 4; ++g) {                                                 \
      const int base = (g & 1) * 4 + (g >> 1) * 8;                                \
      sh[2 * g]     = __shfl_xor(hi ? pw[base + 0] : pw[base + 2], 32);           \
      sh[2 * g + 1] = __shfl_xor(hi ? pw[base + 1] : pw[base + 3], 32);           \
    }                                                                             \
    _Pragma("unroll")                                                             \
    for (int g = 0; g < 4; ++g) {                                                 \
      const int base = (g & 1) * 4 + (g >> 1) * 8;                                \
      int4 bi = { (int)(hi ? sh[2 * g]     : pw[base + 0]),                       \
                  (int)(hi ? sh[2 * g + 1] : pw[base + 1]),                       \
                  (int)(hi ? pw[base + 2] : sh[2 * g]),                           \
                  (int)(hi ? pw[base + 3] : sh[2 * g + 1]) };                     \
      bf16x8 pb = *(bf16x8*)&bi;                                                  \
      bf16x8 v0 = *(const bf16x8*)(ra[g][0] + 16384 + (BUF) * 8192);              \
      bf16x8 v1 = *(const bf16x8*)(ra[g][1] + 16384 + (BUF) * 8192);              \
      o0 = mfma32(v0, pb, o0);                                                    \
      o1 = mfma32(v1, pb, o1);                                                    \
    }                                                                             \
    __syncthreads();                                                              \
  }

  for (int s0 = 0; s0 < S_; s0 += 128) {
    ATTN_TILE(0, s0)
    ATTN_TILE(1, s0 + 64)
  }
#undef ATTN_TILE

  // ---- finalize: one shuffle for the full row-sum; per-lane scalar normalize
  l_r += __shfl_xor(l_r, 32);
  const float inv = 1.0f / l_r;
  bf16* Ob = Oa + ((size_t)(b * S_ + t)) * D_ + h * DH_;
#pragma unroll
  for (int g = 0; g < 4; ++g) {
    bf16x4 u0 = {(bf16)(o0[4 * g + 0] * inv), (bf16)(o0[4 * g + 1] * inv),
                 (bf16)(o0[4 * g + 2] * inv), (bf16)(o0[4 * g + 3] * inv)};
    *(bf16x4*)&Ob[8 * g + 4 * hi] = u0;
    bf16x4 u1 = {(bf16)(o1[4 * g + 0] * inv), (bf16)(o1[4 * g + 1] * inv),
                 (bf16)(o1[4 * g + 2] * inv), (bf16)(o1[4 * g + 3] * inv)};
    *(bf16x4*)&Ob[32 + 8 * g + 4 * hi] = u1;
  }
}

// ---------------- launch ----------------
extern "C" void kernel_launch(void* const* d_in, const int* in_sizes, int n_in,
                              void* d_out, int out_size, void* d_ws, size_t ws_size,
                              hipStream_t stream) {
  const float* Xq   = (const float*)d_in[0];
  const float* Xkv  = (const float*)d_in[1];
  const float* Wq   = (const float*)d_in[2];
  const float* Wk   = (const float*)d_in[3];
  const float* Wv   = (const float*)d_in[4];
  const float* Wo   = (const float*)d_in[5];
  const float* relb = (const float*)d_in[6];
  float* out = (float*)d_out;

  char* ws = (char*)d_ws;
  const size_t SZ_X = (size_t)M_ * D_ * 2;   // 16 MB
  const size_t SZ_W = (size_t)D_ * D_ * 2;   // 2 MB
  bf16* Xq_b  = (bf16*)(ws);
  bf16* Xkv_b = (bf16*)(ws + SZ_X);
  bf16* Wq_t  = (bf16*)(ws + 2 * SZ_X);
  bf16* Wk_t  = (bf16*)(ws + 2 * SZ_X + SZ_W);
  bf16* Wv_t  = (bf16*)(ws + 2 * SZ_X + 2 * SZ_W);
  bf16* Wo_t  = (bf16*)(ws + 2 * SZ_X + 3 * SZ_W);
  bf16* Qb    = (bf16*)(ws + 2 * SZ_X + 4 * SZ_W);
  bf16* Kbuf  = (bf16*)(ws + 3 * SZ_X + 4 * SZ_W);
  bf16* Vt    = (bf16*)(ws + 4 * SZ_X + 4 * SZ_W);
  bf16* Ab    = (bf16*)(ws + 5 * SZ_X + 4 * SZ_W);
  float* tab  = (float*)(ws + 6 * SZ_X + 4 * SZ_W);  // 16*4096 f32

  cast2_kernel<<<16384, 256, 0, stream>>>(Xq, Xkv, Xq_b, Xkv_b);
  transpose_cast4_kernel<<<dim3(32, 32, 4), dim3(32, 8), 0, stream>>>(
      Wq, Wk, Wv, Wo, Wq_t, Wk_t, Wv_t, Wo_t);
  bias_table_kernel<<<256, 256, 0, stream>>>(relb, tab);

  proj_gemm_kernel<<<1536, 256, 0, stream>>>(
      Xq_b, Xkv_b, Wq_t, Wk_t, Wv_t, Qb, Kbuf, Vt);
  attn_kernel<<<512, 512, 0, stream>>>(Qb, Kbuf, Vt, tab, Ab);
  gemm_out_kernel<<<512, 256, 0, stream>>>(Ab, Wo_t, out);
}